// Round 1
// baseline (64.689 us; speedup 1.0000x reference)
//
#include <hip/hip_runtime.h>

constexpr int NB = 32;    // batch
constexpr int NS = 4096;  // sequence
constexpr int ND = 512;   // feature dim

// ---------------------------------------------------------------------------
// Pass 1: one streaming pass over x.
// Grid: (nchunk, NB) blocks of 256 threads (4 waves).
// Each wave handles rows of the chunk; per row:
//   - 64 lanes * 8 floats (two float4: d=4*lane and d=256+4*lane) cover D=512
//   - dot with W fragments (held in registers), wave-64 shuffle reduce
//   - s = tanh(dot + bias[i]); e = exp(s)   (s in (-1,1) -> no max needed)
//   - e written to the weights output region (unnormalized)
//   - context partial c[d] += x[d]*e accumulated in registers
// Block epilogue: combine 4 waves' partials through LDS, write per-chunk
// partial Z and partial context vector to workspace.
// ---------------------------------------------------------------------------
__global__ __launch_bounds__(256) void attn_pass1(
    const float* __restrict__ x, const float* __restrict__ W,
    const float* __restrict__ bias,
    float* __restrict__ e_out,   // [NB*NS]   (weights region of d_out)
    float* __restrict__ Zp,      // [NB*nchunk]
    float* __restrict__ Cp,      // [NB*nchunk*ND]
    int nchunk, int chunk)
{
    const int b    = blockIdx.y;
    const int ch   = blockIdx.x;
    const int tid  = threadIdx.x;
    const int wv   = tid >> 6;      // 0..3
    const int lane = tid & 63;

    const float4 w1 = *(const float4*)(W + 4 * lane);
    const float4 w2 = *(const float4*)(W + 256 + 4 * lane);

    const float* xb = x + (size_t)b * NS * ND;
    const int row0 = ch * chunk;

    float4 c1 = make_float4(0.f, 0.f, 0.f, 0.f);
    float4 c2 = make_float4(0.f, 0.f, 0.f, 0.f);
    float zacc = 0.f;

    // chunk is a multiple of 8; waves 0..3 each process pairs (r, r+4).
    for (int r = wv; r < chunk; r += 8) {
        const int ia = row0 + r;
        const int ib = ia + 4;
        const float* xra = xb + (size_t)ia * ND;
        const float* xrb = xb + (size_t)ib * ND;
        float4 a1 = *(const float4*)(xra + 4 * lane);
        float4 a2 = *(const float4*)(xra + 256 + 4 * lane);
        float4 b1 = *(const float4*)(xrb + 4 * lane);
        float4 b2 = *(const float4*)(xrb + 256 + 4 * lane);

        float pa = a1.x * w1.x + a1.y * w1.y + a1.z * w1.z + a1.w * w1.w
                 + a2.x * w2.x + a2.y * w2.y + a2.z * w2.z + a2.w * w2.w;
        float pb = b1.x * w1.x + b1.y * w1.y + b1.z * w1.z + b1.w * w1.w
                 + b2.x * w2.x + b2.y * w2.y + b2.z * w2.z + b2.w * w2.w;
        #pragma unroll
        for (int m = 32; m >= 1; m >>= 1) {
            pa += __shfl_xor(pa, m);
            pb += __shfl_xor(pb, m);
        }
        float ea = __expf(tanhf(pa + bias[ia]));
        float eb = __expf(tanhf(pb + bias[ib]));
        if (lane == 0) {
            e_out[(size_t)b * NS + ia] = ea;
            e_out[(size_t)b * NS + ib] = eb;
        }
        zacc += ea + eb;
        c1.x += a1.x * ea + b1.x * eb;
        c1.y += a1.y * ea + b1.y * eb;
        c1.z += a1.z * ea + b1.z * eb;
        c1.w += a1.w * ea + b1.w * eb;
        c2.x += a2.x * ea + b2.x * eb;
        c2.y += a2.y * ea + b2.y * eb;
        c2.z += a2.z * ea + b2.z * eb;
        c2.w += a2.w * ea + b2.w * eb;
    }

    // Combine the 4 waves through LDS.
    __shared__ __align__(16) float lc[4][ND];
    __shared__ float lz[4];
    *(float4*)&lc[wv][4 * lane]       = c1;
    *(float4*)&lc[wv][256 + 4 * lane] = c2;
    if (lane == 0) lz[wv] = zacc;
    __syncthreads();

    float* cp = Cp + ((size_t)b * nchunk + ch) * ND;
    for (int d = tid; d < ND; d += 256)
        cp[d] = lc[0][d] + lc[1][d] + lc[2][d] + lc[3][d];
    if (tid == 0)
        Zp[b * nchunk + ch] = lz[0] + lz[1] + lz[2] + lz[3];
}

// ---------------------------------------------------------------------------
// Pass 2: per-batch finalize. Grid: NB blocks of 256 threads.
//   Z = sum of chunk partials; context = (sum of chunk c) / Z;
//   weights[i] = e[i] / Z  (in-place rescale of the e values).
// ---------------------------------------------------------------------------
__global__ __launch_bounds__(256) void attn_pass2(
    const float* __restrict__ Zp, const float* __restrict__ Cp,
    float* __restrict__ w_inout,   // [NB*NS]
    float* __restrict__ ctx,       // [NB*ND]
    int nchunk)
{
    const int b = blockIdx.x;
    __shared__ float zs;

    if (threadIdx.x < 64) {
        float z = (threadIdx.x < nchunk) ? Zp[b * nchunk + threadIdx.x] : 0.f;
        #pragma unroll
        for (int m = 32; m >= 1; m >>= 1) z += __shfl_xor(z, m);
        if (threadIdx.x == 0) zs = z;
    }
    __syncthreads();
    const float invZ = 1.0f / zs;

    const float* cpb = Cp + (size_t)b * nchunk * ND;
    for (int d = threadIdx.x; d < ND; d += 256) {
        float v = 0.f;
        for (int c = 0; c < nchunk; ++c) v += cpb[(size_t)c * ND + d];
        ctx[b * ND + d] = v * invZ;
    }
    float* wb = w_inout + (size_t)b * NS;
    for (int i = threadIdx.x; i < NS; i += 256)
        wb[i] *= invZ;
}

extern "C" void kernel_launch(void* const* d_in, const int* in_sizes, int n_in,
                              void* d_out, int out_size, void* d_ws, size_t ws_size,
                              hipStream_t stream) {
    const float* x    = (const float*)d_in[0];
    const float* W    = (const float*)d_in[1];
    const float* bias = (const float*)d_in[2];

    float* ctx = (float*)d_out;            // [NB*ND]
    float* wts = ctx + NB * ND;            // [NB*NS]

    // Pick the largest chunk count whose partials fit in the workspace.
    int nchunk = 32;
    while (nchunk > 1 &&
           (size_t)4 * NB * nchunk * (1 + ND) > ws_size)
        nchunk >>= 1;
    const int chunk = NS / nchunk;

    float* Zp = (float*)d_ws;
    float* Cp = Zp + (size_t)NB * nchunk;

    hipLaunchKernelGGL(attn_pass1, dim3(nchunk, NB), dim3(256), 0, stream,
                       x, W, bias, wts, Zp, Cp, nchunk, chunk);
    hipLaunchKernelGGL(attn_pass2, dim3(NB), dim3(256), 0, stream,
                       Zp, Cp, wts, ctx, nchunk);
}